// Round 2
// baseline (392.585 us; speedup 1.0000x reference)
//
#include <hip/hip_runtime.h>
#include <math.h>

#define NODES   62
#define DEGC    16
#define NGRAPH  4096
#define NTOT    (NGRAPH*NODES)      // 253952
#define FIN     32
#define HIDC    64
#define XLSTR   68                  // padded stride (floats), 272B = 17*16 -> float4 aligned

// ---------------------------------------------------------------------------
// Kernel A: GATv2 layer 1, one block per 62-node graph.
//   x[N,32] -> h[N,64]; also per-block BN partials (sum, sumsq per channel).
// ---------------------------------------------------------------------------
__global__ __launch_bounds__(256, 2) void gat1_kernel(
    const float* __restrict__ x,
    const int*   __restrict__ esrc,
    const float* __restrict__ Wl, const float* __restrict__ bl,
    const float* __restrict__ Wr, const float* __restrict__ br,
    const float* __restrict__ att, const float* __restrict__ bias,
    float* __restrict__ h, float* __restrict__ part)
{
    __shared__ float4 xs4[NODES][FIN/4];       // 62*8 float4
    __shared__ float  xls[NODES*XLSTR];        // xl = x@Wl + bl
    __shared__ float  xrs[NODES*XLSTR];        // xr = x@Wr + br
    __shared__ int    srcs[NODES*DEGC];        // local src indices
    __shared__ float  red[2*4*16*4];           // BN partial reduce [sum/sq][wave][l16][comp]

    const int tid   = threadIdx.x;
    const int g     = blockIdx.x;
    const int nbase = g * NODES;

    // ---- stage x (float4, coalesced) ----
    const float4* xg = (const float4*)x + (size_t)nbase * (FIN/4);
    for (int idx = tid; idx < NODES*(FIN/4); idx += 256)
        xs4[idx >> 3][idx & 7] = xg[idx];

    // ---- stage edge sources (made graph-local) ----
    const int* eg = esrc + (size_t)nbase * DEGC;
    for (int idx = tid; idx < NODES*DEGC; idx += 256)
        srcs[idx] = eg[idx] - nbase;

    // ---- per-thread weight columns in registers (c fixed per thread) ----
    const int c = tid & 63;
    float wl[FIN], wr[FIN];
#pragma unroll
    for (int k = 0; k < FIN; ++k) {
        wl[k] = Wl[k*HIDC + c];
        wr[k] = Wr[k*HIDC + c];
    }
    const float blc = bl[c], brc = br[c];

    __syncthreads();

    // ---- xl, xr for all 62 nodes ----
    for (int idx = tid; idx < NODES*HIDC; idx += 256) {
        const int node = idx >> 6;            // idx&63 == c by construction
        float al = blc, ar = brc;
#pragma unroll
        for (int q = 0; q < FIN/4; ++q) {
            const float4 v = xs4[node][q];
            al += v.x*wl[4*q+0] + v.y*wl[4*q+1] + v.z*wl[4*q+2] + v.w*wl[4*q+3];
            ar += v.x*wr[4*q+0] + v.y*wr[4*q+1] + v.z*wr[4*q+2] + v.w*wr[4*q+3];
        }
        xls[node*XLSTR + c] = al;
        xrs[node*XLSTR + c] = ar;
    }
    __syncthreads();

    // ---- attention + aggregation: 16 lanes per node, 4 channels per lane ----
    const int wave = tid >> 6;
    const int lane = tid & 63;
    const int grp  = lane >> 4;               // node sub-group within wave
    const int l16  = lane & 15;
    const int cl   = l16 * 4;                 // channel base for this lane

    const float4 attv  = *(const float4*)(att  + cl);
    const float4 biasv = *(const float4*)(bias + cl);

    float sx=0.f, sy=0.f, sz=0.f, sw=0.f;     // BN sums
    float qx=0.f, qy=0.f, qz=0.f, qw=0.f;     // BN sumsq

    for (int pass = 0; pass < 4; ++pass) {
        const int node = pass*16 + wave*4 + grp;
        if (node < NODES) {
            const float4 xrv = *(const float4*)(xrs + node*XLSTR + cl);
            float av[17];
            // alphas: dot(leaky_relu(xl[src]+xr[node]), att), 16-lane reduce
#pragma unroll
            for (int e = 0; e < 17; ++e) {
                const int s = (e < DEGC) ? srcs[node*DEGC + e] : node;
                const float4 xlv = *(const float4*)(xls + s*XLSTR + cl);
                float vx = xlv.x + xrv.x; vx = vx > 0.f ? vx : 0.2f*vx;
                float vy = xlv.y + xrv.y; vy = vy > 0.f ? vy : 0.2f*vy;
                float vz = xlv.z + xrv.z; vz = vz > 0.f ? vz : 0.2f*vz;
                float vw = xlv.w + xrv.w; vw = vw > 0.f ? vw : 0.2f*vw;
                float a = vx*attv.x + vy*attv.y + vz*attv.z + vw*attv.w;
                a += __shfl_xor(a, 1);
                a += __shfl_xor(a, 2);
                a += __shfl_xor(a, 4);
                a += __shfl_xor(a, 8);
                av[e] = a;                    // all 16 lanes hold full alpha
            }
            // softmax over 17 incoming edges (in registers, redundant per lane)
            float m = av[0];
#pragma unroll
            for (int e = 1; e < 17; ++e) m = fmaxf(m, av[e]);
            float ssum = 0.f;
#pragma unroll
            for (int e = 0; e < 17; ++e) { av[e] = __expf(av[e] - m); ssum += av[e]; }
            const float inv = 1.f / (ssum + 1e-16f);

            // weighted aggregation of xl[src]
            float ax=0.f, ay=0.f, az=0.f, aw=0.f;
#pragma unroll
            for (int e = 0; e < 17; ++e) {
                const int s = (e < DEGC) ? srcs[node*DEGC + e] : node;
                const float4 xlv = *(const float4*)(xls + s*XLSTR + cl);
                ax += av[e]*xlv.x; ay += av[e]*xlv.y;
                az += av[e]*xlv.z; aw += av[e]*xlv.w;
            }
            ax = ax*inv + biasv.x; ay = ay*inv + biasv.y;
            az = az*inv + biasv.z; aw = aw*inv + biasv.w;

            float4 hv; hv.x = ax; hv.y = ay; hv.z = az; hv.w = aw;
            *(float4*)(h + (size_t)(nbase + node)*HIDC + cl) = hv;

            sx += ax; sy += ay; sz += az; sw += aw;
            qx += ax*ax; qy += ay*ay; qz += az*az; qw += aw*aw;
        }
    }

    // ---- reduce BN partials across the 4 sub-groups of each wave ----
    sx += __shfl_xor(sx,16); sx += __shfl_xor(sx,32);
    sy += __shfl_xor(sy,16); sy += __shfl_xor(sy,32);
    sz += __shfl_xor(sz,16); sz += __shfl_xor(sz,32);
    sw += __shfl_xor(sw,16); sw += __shfl_xor(sw,32);
    qx += __shfl_xor(qx,16); qx += __shfl_xor(qx,32);
    qy += __shfl_xor(qy,16); qy += __shfl_xor(qy,32);
    qz += __shfl_xor(qz,16); qz += __shfl_xor(qz,32);
    qw += __shfl_xor(qw,16); qw += __shfl_xor(qw,32);
    if (lane < 16) {
        float* rs = red + ((0*4 + wave)*16 + l16)*4;
        float* rq = red + ((1*4 + wave)*16 + l16)*4;
        rs[0]=sx; rs[1]=sy; rs[2]=sz; rs[3]=sw;
        rq[0]=qx; rq[1]=qy; rq[2]=qz; rq[3]=qw;
    }
    __syncthreads();
    if (tid < HIDC) {
        const int cc = tid, li = cc >> 2, comp = cc & 3;
        float s = 0.f, q = 0.f;
#pragma unroll
        for (int w = 0; w < 4; ++w) {
            s += red[((0*4 + w)*16 + li)*4 + comp];
            q += red[((1*4 + w)*16 + li)*4 + comp];
        }
        part[(size_t)cc        *NGRAPH + g] = s;
        part[(size_t)(HIDC+cc) *NGRAPH + g] = q;
    }
}

// ---------------------------------------------------------------------------
// Kernel B: reduce BN partials; fold BN affine into layer-2 weights.
//   fw[0:64]=scale*Wl2, fw[64:128]=scale*Wr2, fw[128]=bl2', fw[129]=br2'
// ---------------------------------------------------------------------------
__global__ __launch_bounds__(1024) void bnfold_kernel(
    const float* __restrict__ part,
    const float* __restrict__ gamma, const float* __restrict__ beta,
    const float* __restrict__ Wl2, const float* __restrict__ bl2,
    const float* __restrict__ Wr2, const float* __restrict__ br2,
    float* __restrict__ fw)
{
    __shared__ float gs[128];
    __shared__ float tmp[128];
    const int tid = threadIdx.x;
    const int v = tid >> 3, sub = tid & 7;
    float s = 0.f;
    for (int j = sub; j < NGRAPH; j += 8) s += part[(size_t)v*NGRAPH + j];
    s += __shfl_xor(s, 1); s += __shfl_xor(s, 2); s += __shfl_xor(s, 4);
    if (sub == 0) gs[v] = s;
    __syncthreads();
    if (tid < HIDC) {
        const int c = tid;
        const float invN = 1.f / (float)NTOT;
        const float mu  = gs[c] * invN;
        const float var = gs[HIDC + c] * invN - mu*mu;
        const float sc  = gamma[c] * rsqrtf(var + 1e-5f);
        const float sh  = beta[c] - mu * sc;
        fw[c]        = sc * Wl2[c];
        fw[HIDC + c] = sc * Wr2[c];
        tmp[c]        = sh * Wl2[c];
        tmp[HIDC + c] = sh * Wr2[c];
    }
    __syncthreads();
    if (tid == 0) {
        float a = bl2[0], b = br2[0];
        for (int c2 = 0; c2 < HIDC; ++c2) { a += tmp[c2]; b += tmp[HIDC + c2]; }
        fw[128] = a; fw[129] = b;
    }
}

// ---------------------------------------------------------------------------
// Kernel C: GATv2 layer 2 (scalar features) + exact GELU, one block per graph.
// ---------------------------------------------------------------------------
__global__ __launch_bounds__(256, 2) void gat2_kernel(
    const float* __restrict__ h,
    const int*   __restrict__ esrc,
    const float* __restrict__ fw,
    const float* __restrict__ att2, const float* __restrict__ bias2,
    float* __restrict__ out)
{
    __shared__ float xl2s[64], xr2s[64];
    __shared__ float wls[HIDC], wrs[HIDC];
    __shared__ int   srcs[NODES*DEGC];

    const int tid   = threadIdx.x;
    const int g     = blockIdx.x;
    const int nbase = g * NODES;

    if (tid < HIDC) { wls[tid] = fw[tid]; wrs[tid] = fw[HIDC + tid]; }
    const int* eg = esrc + (size_t)nbase * DEGC;
    for (int idx = tid; idx < NODES*DEGC; idx += 256)
        srcs[idx] = eg[idx] - nbase;
    __syncthreads();

    // xl2/xr2 = h . fw (+ folded bias): 4 lanes per node, 16 channels each
    if (tid < NODES*4) {
        const int node = tid >> 2, sub = tid & 3;
        const float4* hp = (const float4*)(h + (size_t)(nbase + node)*HIDC + sub*16);
        float al = 0.f, ar = 0.f;
#pragma unroll
        for (int q = 0; q < 4; ++q) {
            const float4 v = hp[q];
            const int cb = sub*16 + q*4;
            al += v.x*wls[cb] + v.y*wls[cb+1] + v.z*wls[cb+2] + v.w*wls[cb+3];
            ar += v.x*wrs[cb] + v.y*wrs[cb+1] + v.z*wrs[cb+2] + v.w*wrs[cb+3];
        }
        al += __shfl_xor(al, 1); al += __shfl_xor(al, 2);
        ar += __shfl_xor(ar, 1); ar += __shfl_xor(ar, 2);
        if (sub == 0) {
            xl2s[node] = al + fw[128];
            xr2s[node] = ar + fw[129];
        }
    }
    __syncthreads();

    if (tid < NODES) {
        const int node = tid;
        const float xr = xr2s[node];
        const float a2 = att2[0];
        float av[17];
        float m = -1e30f;
#pragma unroll
        for (int e = 0; e < 17; ++e) {
            const int s = (e < DEGC) ? srcs[node*DEGC + e] : node;
            float v = xl2s[s] + xr;
            v = v > 0.f ? v : 0.2f*v;
            v *= a2;
            av[e] = v;
            m = fmaxf(m, v);
        }
        float ssum = 0.f, acc = 0.f;
#pragma unroll
        for (int e = 0; e < 17; ++e) {
            const int s = (e < DEGC) ? srcs[node*DEGC + e] : node;
            const float p = __expf(av[e] - m);
            ssum += p;
            acc  += p * xl2s[s];
        }
        float o = acc / (ssum + 1e-16f) + bias2[0];
        // exact GELU: 0.5*x*(1+erf(x/sqrt(2)))
        const float gel = 0.5f * o * (1.f + erff(o * 0.70710678118654752f));
        out[(size_t)g*NODES + node] = gel;
    }
}

extern "C" void kernel_launch(void* const* d_in, const int* in_sizes, int n_in,
                              void* d_out, int out_size, void* d_ws, size_t ws_size,
                              hipStream_t stream) {
    const float* x     = (const float*)d_in[0];
    const int*   edge  = (const int*)d_in[1];     // [2,E]; src = first E
    const float* Wl1   = (const float*)d_in[2];
    const float* bl1   = (const float*)d_in[3];
    const float* Wr1   = (const float*)d_in[4];
    const float* br1   = (const float*)d_in[5];
    const float* att1  = (const float*)d_in[6];
    const float* bias1 = (const float*)d_in[7];
    const float* gamma = (const float*)d_in[8];
    const float* beta  = (const float*)d_in[9];
    const float* Wl2   = (const float*)d_in[10];
    const float* bl2   = (const float*)d_in[11];
    const float* Wr2   = (const float*)d_in[12];
    const float* br2   = (const float*)d_in[13];
    const float* att2  = (const float*)d_in[14];
    const float* bias2 = (const float*)d_in[15];
    float* out = (float*)d_out;

    float* h    = (float*)d_ws;                       // NTOT*64 floats
    float* part = h + (size_t)NTOT * HIDC;            // 128*4096 floats
    float* fw   = part + (size_t)128 * NGRAPH;        // 130 floats

    gat1_kernel<<<NGRAPH, 256, 0, stream>>>(x, edge, Wl1, bl1, Wr1, br1,
                                            att1, bias1, h, part);
    bnfold_kernel<<<1, 1024, 0, stream>>>(part, gamma, beta, Wl2, bl2, Wr2, br2, fw);
    gat2_kernel<<<NGRAPH, 256, 0, stream>>>(h, edge, fw, att2, bias2, out);
}